// Round 6
// baseline (241.452 us; speedup 1.0000x reference)
//
#include <hip/hip_runtime.h>
#include <hip/hip_bf16.h>
#include <math.h>
#include <float.h>

#define N_PTS 16384
#define NVERT 6890
#define RESO 256
#define C_LAT 192
#define VIEW_DIM 27
#define ROWS 64          // points per mega-block
#define VHALF 3448       // vertices staged per half (x16B = 55168 B <= 81920)

typedef __hip_bfloat16 bf16;
typedef __bf16 bf16x8 __attribute__((ext_vector_type(8)));
typedef float f32x4 __attribute__((ext_vector_type(4)));

// ---------------- latent transpose: [C][H][W] fp32 -> [H][W][C] bf16 ----------------
__global__ __launch_bounds__(256) void transpose_latent(const float* __restrict__ lat,
                                                        bf16* __restrict__ latT) {
    __shared__ float tile[C_LAT][65];
    int b = blockIdx.x;            // 1024 blocks
    int y = b >> 2;
    int x0 = (b & 3) << 6;
    int t = threadIdx.x;
    #pragma unroll
    for (int i = 0; i < (C_LAT * 64) / 256; ++i) {   // 48 iters
        int e = i * 256 + t;
        int c = e >> 6, xi = e & 63;
        tile[c][xi] = lat[c * (RESO * RESO) + y * RESO + x0 + xi];
    }
    __syncthreads();
    #pragma unroll
    for (int i = 0; i < (C_LAT * 64) / 256; ++i) {
        int e = i * 256 + t;
        int xi = e / C_LAT, c = e % C_LAT;
        latT[(size_t)(y * RESO + x0 + xi) * C_LAT + c] = __float2bfloat16(tile[c][xi]);
    }
}

// ---------------- prep: weights->bf16 (padded) + packed vertex float4 ----------------
__global__ __launch_bounds__(256) void prep(const float* __restrict__ w0,
                                            const float* __restrict__ w1,
                                            const float* __restrict__ w2,
                                            const float* __restrict__ w3,
                                            const float* __restrict__ V,
                                            bf16* __restrict__ W0b,   // [256][128]
                                            bf16* __restrict__ W1b,   // [256][256]
                                            bf16* __restrict__ W2b,   // [256][384]
                                            bf16* __restrict__ W3b,   // [128][256]
                                            float4* __restrict__ V4) {
    int i = blockIdx.x * 256 + threadIdx.x;   // 384*256 = 98304
    if (i < 256 * 128) {
        int n = i >> 7, k = i & 127;
        W0b[i] = __float2bfloat16((k < 127) ? w0[n * 127 + k] : 0.0f);
    }
    if (i < 256 * 256) W1b[i] = __float2bfloat16(w1[i]);
    if (i < 256 * 384) {
        int n = i / 384, k = i % 384;
        W2b[i] = __float2bfloat16((k < 347) ? w2[n * 347 + k] : 0.0f);
    }
    if (i < 128 * 256) W3b[i] = __float2bfloat16(w3[i]);
    if (i < NVERT) {
        float x = V[i * 3 + 0], y = V[i * 3 + 1], z = V[i * 3 + 2];
        float v2 = __fadd_rn(__fadd_rn(__fmul_rn(x, x), __fmul_rn(y, y)), __fmul_rn(z, z));
        V4[i] = make_float4(x, y, z, v2);
    }
}

// swizzled LDS byte offset within a row-major bf16 tile (row stride LDB bytes).
// (row&7)<<4 <= 112 < 256 <= LDB, so the XOR stays inside the row.
__device__ __forceinline__ int swz(int row, int kbyte, int LDB) {
    return row * LDB + (kbyte ^ ((row & 7) << 4));
}

// ---------------- mega: NN + bilinear + embed + 4-layer MLP + heads ----------------
__global__ __launch_bounds__(512) void mega(const float* __restrict__ P,
                                            const float4* __restrict__ V4,
                                            const float* __restrict__ vts_uv,
                                            const bf16* __restrict__ latT,
                                            const float* __restrict__ view_dir,
                                            const bf16* __restrict__ W0, const float* __restrict__ b0,
                                            const bf16* __restrict__ W1, const float* __restrict__ b1,
                                            const bf16* __restrict__ W2, const float* __restrict__ b2,
                                            const bf16* __restrict__ W3, const float* __restrict__ b3,
                                            const float* __restrict__ w_alpha, const float* __restrict__ b_alpha,
                                            const float* __restrict__ w_rgb, const float* __restrict__ b_rgb,
                                            float* __restrict__ out) {
    // smem_all is time-shared:
    //   Phase 1 (NN): vbuf = float4[VHALF] (55168 B) overlays bufA|bufB
    //   Phases 2+ : bufA (64x LDB512), bufB (64x LDB512), bufC (64x LDB256)
    __shared__ __align__(16) char smem_all[81920];
    __shared__ float redF[8][ROWS];
    __shared__ int   redI[8][ROWS];
    __shared__ float hunv[3][ROWS];
    char* bufA = smem_all;
    char* bufB = smem_all + 32768;
    char* bufC = smem_all + 65536;

    const int t = threadIdx.x;
    const int lane = t & 63;
    const int w = t >> 6;
    const int lr = lane & 15, lg = lane >> 4;
    const int n0 = blockIdx.x * ROWS;

    // ---- Phase 1: NN argmin, LDS-staged vertices, exact ref arithmetic ----
    // lane <-> point; wave <-> sub-range of the staged chunk; ties by min index
    {
        float4* vbuf = (float4*)smem_all;
        int n = n0 + lane;
        float px = P[n * 3 + 0], py = P[n * 3 + 1], pz = P[n * 3 + 2];
        float p2 = __fadd_rn(__fadd_rn(__fmul_rn(px, px), __fmul_rn(py, py)), __fmul_rn(pz, pz));
        float best = FLT_MAX;
        int bi = 0;
        #pragma unroll
        for (int half = 0; half < 2; ++half) {
            int base = half * VHALF;
            int cnt = min(VHALF, NVERT - base);
            __syncthreads();                       // vbuf reuse guard
            for (int i = t; i < cnt; i += 512) vbuf[i] = V4[base + i];
            __syncthreads();
            int per = (cnt + 7) >> 3;
            int s0 = w * per, s1 = min(s0 + per, cnt);
            #pragma unroll 4
            for (int v = s0; v < s1; ++v) {
                float4 q = vbuf[v];                // uniform addr -> LDS broadcast
                float dot = fmaf(pz, q.z, fmaf(py, q.y, __fmul_rn(px, q.x)));
                float d2 = __fsub_rn(__fadd_rn(p2, q.w), __fmul_rn(2.0f, dot));
                int gi = base + v;
                if (d2 < best || (d2 == best && gi < bi)) { best = d2; bi = gi; }
            }
        }
        redF[w][lane] = best;
        redI[w][lane] = bi;
    }
    __syncthreads();
    if (t < ROWS) {
        float best = FLT_MAX;
        int bi = 0x7fffffff;
        #pragma unroll
        for (int ww = 0; ww < 8; ++ww) {          // ties -> lowest global index (numpy argmin)
            float d = redF[ww][t];
            int ix = redI[ww][t];
            if (d < best || (d == best && ix < bi)) { best = d; bi = ix; }
        }
        hunv[0][t] = __fsqrt_rn(fmaxf(best, 1e-12f));
        hunv[1][t] = vts_uv[bi * 2 + 0];
        hunv[2][t] = vts_uv[bi * 2 + 1];
    }
    __syncthreads();

    // ---- Phase 2a: bilinear fusion (wave w handles points w*8..w*8+7; lane = channel) ----
    {
        #pragma unroll
        for (int pp = 0; pp < 8; ++pp) {
            int p = w * 8 + pp;
            float h = hunv[0][p], u = hunv[1][p], vv = hunv[2][p];
            float hn = __fmul_rn(__fadd_rn(__fdiv_rn(h, 0.1f), 1.0f), 0.5f);
            float fsum = 0.0f;
            #pragma unroll
            for (int pl = 0; pl < 3; ++pl) {
                float xc = (pl == 2) ? hn : u;
                float yc = (pl == 1) ? hn : vv;
                float x = fminf(fmaxf(xc, 0.0f), 1.0f) * 255.0f;
                float y = fminf(fmaxf(yc, 0.0f), 1.0f) * 255.0f;
                float x0 = floorf(x), y0 = floorf(y);
                float wx = x - x0, wy = y - y0;
                int x0i = min(max((int)x0, 0), 255), y0i = min(max((int)y0, 0), 255);
                int x1i = min(x0i + 1, 255), y1i = min(y0i + 1, 255);
                int co = pl * 64 + lane;
                float f00 = __bfloat162float(latT[(size_t)(y0i * 256 + x0i) * C_LAT + co]);
                float f01 = __bfloat162float(latT[(size_t)(y0i * 256 + x1i) * C_LAT + co]);
                float f10 = __bfloat162float(latT[(size_t)(y1i * 256 + x0i) * C_LAT + co]);
                float f11 = __bfloat162float(latT[(size_t)(y1i * 256 + x1i) * C_LAT + co]);
                fsum += f00 * (1 - wx) * (1 - wy) + f01 * wx * (1 - wy) + f10 * (1 - wx) * wy + f11 * wx * wy;
            }
            bf16 fb = __float2bfloat16(fsum / 3.0f);
            *(bf16*)(bufA + swz(p, lane * 2, 256)) = fb;             // X1 cols 0..63
            *(bf16*)(bufC + swz(p, (27 + lane) * 2, 256)) = fb;      // extra cols 27..90
        }
    }

    // ---- Phase 2b: embed + view_dir + zero pads (thread p=t>>3, i=t&7) ----
    {
        int p = t >> 3, i = t & 7;
        float h = hunv[0][p], u = hunv[1][p], vv = hunv[2][p];
        #pragma unroll
        for (int r = 0; r < 8; ++r) {
            int j = i + r * 8;          // 0..63
            float val;
            if (j == 63) {
                val = 0.0f;             // X1 col 127 pad
            } else if (j < 3) {
                val = (j == 0) ? h : ((j == 1) ? u : vv);
            } else if (j < 33) {
                int e = j - 3;
                int d = e / 10, k = e % 10;
                float pv = (d == 0) ? h : ((d == 1) ? u : vv);
                val = sinf(pv * (float)(1 << k));
            } else {
                int e = j - 33;
                int d = e / 10, k = e % 10;
                float pv = (d == 0) ? h : ((d == 1) ? u : vv);
                val = cosf(pv * (float)(1 << k));
            }
            *(bf16*)(bufA + swz(p, (64 + j) * 2, 256)) = __float2bfloat16(val);
        }
        #pragma unroll
        for (int r = 0; r < 4; ++r) {
            int c = i + r * 8;          // 0..31
            if (c < VIEW_DIM)
                *(bf16*)(bufC + swz(p, c * 2, 256)) =
                    __float2bfloat16(view_dir[(size_t)(n0 + p) * VIEW_DIM + c]);
        }
        #pragma unroll
        for (int r = 0; r < 5; ++r) {
            int c = 91 + i + r * 8;     // zero extra cols 91..127
            if (c < 128)
                *(bf16*)(bufC + swz(p, c * 2, 256)) = __float2bfloat16(0.0f);
        }
    }
    __syncthreads();

    const int wm = w >> 2, wn = w & 3;

    // ---- L0: A=bufA(LDB 256, K=128)  B=W0[256][128]  -> relu -> bufB(LDB 512) ----
    {
        f32x4 acc[2][4] = {};
        #pragma unroll
        for (int ks = 0; ks < 4; ++ks) {
            int kt = ks * 32;
            bf16x8 a[2], b[4];
            #pragma unroll
            for (int m = 0; m < 2; ++m) {
                int row = wm * 32 + m * 16 + lr;
                a[m] = *(const bf16x8*)(bufA + swz(row, (kt + lg * 8) * 2, 256));
            }
            #pragma unroll
            for (int nn = 0; nn < 4; ++nn) {
                int col = wn * 64 + nn * 16 + lr;
                b[nn] = *(const bf16x8*)(W0 + (size_t)col * 128 + kt + lg * 8);
            }
            #pragma unroll
            for (int m = 0; m < 2; ++m)
                #pragma unroll
                for (int nn = 0; nn < 4; ++nn)
                    acc[m][nn] = __builtin_amdgcn_mfma_f32_16x16x32_bf16(a[m], b[nn], acc[m][nn], 0, 0, 0);
        }
        #pragma unroll
        for (int nn = 0; nn < 4; ++nn) {
            int col = wn * 64 + nn * 16 + lr;
            float bv = b0[col];
            #pragma unroll
            for (int m = 0; m < 2; ++m)
                #pragma unroll
                for (int j = 0; j < 4; ++j) {
                    int row = wm * 32 + m * 16 + lg * 4 + j;
                    *(bf16*)(bufB + swz(row, col * 2, 512)) =
                        __float2bfloat16(fmaxf(acc[m][nn][j] + bv, 0.0f));
                }
        }
    }
    __syncthreads();

    // ---- L1: A=bufB(512, K=256)  B=W1[256][256]  -> relu -> bufA(512) (net1) ----
    {
        f32x4 acc[2][4] = {};
        #pragma unroll
        for (int ks = 0; ks < 8; ++ks) {
            int kt = ks * 32;
            bf16x8 a[2], b[4];
            #pragma unroll
            for (int m = 0; m < 2; ++m) {
                int row = wm * 32 + m * 16 + lr;
                a[m] = *(const bf16x8*)(bufB + swz(row, (kt + lg * 8) * 2, 512));
            }
            #pragma unroll
            for (int nn = 0; nn < 4; ++nn) {
                int col = wn * 64 + nn * 16 + lr;
                b[nn] = *(const bf16x8*)(W1 + (size_t)col * 256 + kt + lg * 8);
            }
            #pragma unroll
            for (int m = 0; m < 2; ++m)
                #pragma unroll
                for (int nn = 0; nn < 4; ++nn)
                    acc[m][nn] = __builtin_amdgcn_mfma_f32_16x16x32_bf16(a[m], b[nn], acc[m][nn], 0, 0, 0);
        }
        #pragma unroll
        for (int nn = 0; nn < 4; ++nn) {
            int col = wn * 64 + nn * 16 + lr;
            float bv = b1[col];
            #pragma unroll
            for (int m = 0; m < 2; ++m)
                #pragma unroll
                for (int j = 0; j < 4; ++j) {
                    int row = wm * 32 + m * 16 + lg * 4 + j;
                    *(bf16*)(bufA + swz(row, col * 2, 512)) =
                        __float2bfloat16(fmaxf(acc[m][nn][j] + bv, 0.0f));
                }
        }
    }
    __syncthreads();

    // ---- L2: A=[bufA(512) K 0..255 | bufC(256) K 256..383]  B=W2[256][384] -> relu -> bufB(512) ----
    {
        f32x4 acc[2][4] = {};
        #pragma unroll
        for (int ks = 0; ks < 12; ++ks) {
            int kt = ks * 32;
            bf16x8 a[2], b[4];
            #pragma unroll
            for (int m = 0; m < 2; ++m) {
                int row = wm * 32 + m * 16 + lr;
                if (kt < 256)
                    a[m] = *(const bf16x8*)(bufA + swz(row, (kt + lg * 8) * 2, 512));
                else
                    a[m] = *(const bf16x8*)(bufC + swz(row, (kt - 256 + lg * 8) * 2, 256));
            }
            #pragma unroll
            for (int nn = 0; nn < 4; ++nn) {
                int col = wn * 64 + nn * 16 + lr;
                b[nn] = *(const bf16x8*)(W2 + (size_t)col * 384 + kt + lg * 8);
            }
            #pragma unroll
            for (int m = 0; m < 2; ++m)
                #pragma unroll
                for (int nn = 0; nn < 4; ++nn)
                    acc[m][nn] = __builtin_amdgcn_mfma_f32_16x16x32_bf16(a[m], b[nn], acc[m][nn], 0, 0, 0);
        }
        #pragma unroll
        for (int nn = 0; nn < 4; ++nn) {
            int col = wn * 64 + nn * 16 + lr;
            float bv = b2[col];
            #pragma unroll
            for (int m = 0; m < 2; ++m)
                #pragma unroll
                for (int j = 0; j < 4; ++j) {
                    int row = wm * 32 + m * 16 + lg * 4 + j;
                    *(bf16*)(bufB + swz(row, col * 2, 512)) =
                        __float2bfloat16(fmaxf(acc[m][nn][j] + bv, 0.0f));
                }
        }
    }
    __syncthreads();

    // ---- L3: A=bufB(512, K=256)  B=W3[128][256]  -> relu -> bufC(256) (A4) ----
    {
        f32x4 acc[2][2] = {};
        #pragma unroll
        for (int ks = 0; ks < 8; ++ks) {
            int kt = ks * 32;
            bf16x8 a[2], b[2];
            #pragma unroll
            for (int m = 0; m < 2; ++m) {
                int row = wm * 32 + m * 16 + lr;
                a[m] = *(const bf16x8*)(bufB + swz(row, (kt + lg * 8) * 2, 512));
            }
            #pragma unroll
            for (int nn = 0; nn < 2; ++nn) {
                int col = wn * 32 + nn * 16 + lr;
                b[nn] = *(const bf16x8*)(W3 + (size_t)col * 256 + kt + lg * 8);
            }
            #pragma unroll
            for (int m = 0; m < 2; ++m)
                #pragma unroll
                for (int nn = 0; nn < 2; ++nn)
                    acc[m][nn] = __builtin_amdgcn_mfma_f32_16x16x32_bf16(a[m], b[nn], acc[m][nn], 0, 0, 0);
        }
        #pragma unroll
        for (int nn = 0; nn < 2; ++nn) {
            int col = wn * 32 + nn * 16 + lr;
            float bv = b3[col];
            #pragma unroll
            for (int m = 0; m < 2; ++m)
                #pragma unroll
                for (int j = 0; j < 4; ++j) {
                    int row = wm * 32 + m * 16 + lg * 4 + j;
                    *(bf16*)(bufC + swz(row, col * 2, 256)) =
                        __float2bfloat16(fmaxf(acc[m][nn][j] + bv, 0.0f));
                }
        }
    }
    __syncthreads();

    // ---- Heads: alpha = w_alpha . net1(bufA) + b ; rgb = w_rgb . A4(bufC) + b ----
    {
        int p = t >> 3, g = t & 7;
        float sa = 0.0f;
        #pragma unroll
        for (int c0 = 0; c0 < 32; ++c0) {
            int col = g * 32 + c0;
            float x = __bfloat162float(*(const bf16*)(bufA + swz(p, col * 2, 512)));
            sa = fmaf(x, w_alpha[col], sa);
        }
        float sr = 0.0f, sg = 0.0f, sb = 0.0f;
        #pragma unroll
        for (int c0 = 0; c0 < 16; ++c0) {
            int col = g * 16 + c0;
            float x = __bfloat162float(*(const bf16*)(bufC + swz(p, col * 2, 256)));
            sr = fmaf(x, w_rgb[0 * 128 + col], sr);
            sg = fmaf(x, w_rgb[1 * 128 + col], sg);
            sb = fmaf(x, w_rgb[2 * 128 + col], sb);
        }
        #pragma unroll
        for (int off = 4; off; off >>= 1) {
            sa += __shfl_xor(sa, off, 64);
            sr += __shfl_xor(sr, off, 64);
            sg += __shfl_xor(sg, off, 64);
            sb += __shfl_xor(sb, off, 64);
        }
        if (g == 0) {
            float4 o = make_float4(sa + b_alpha[0], sr + b_rgb[0], sg + b_rgb[1], sb + b_rgb[2]);
            *(float4*)(out + (size_t)(n0 + p) * 4) = o;
        }
    }
}

extern "C" void kernel_launch(void* const* d_in, const int* in_sizes, int n_in,
                              void* d_out, int out_size, void* d_ws, size_t ws_size,
                              hipStream_t stream) {
    (void)in_sizes; (void)n_in; (void)out_size; (void)ws_size;
    const float* sampled_pts  = (const float*)d_in[0];
    const float* smpl_verts   = (const float*)d_in[1];
    const float* view_dir     = (const float*)d_in[2];
    const float* input_latent = (const float*)d_in[3];
    const float* vts_uv       = (const float*)d_in[4];
    const float* w_geo0 = (const float*)d_in[5];
    const float* b_geo0 = (const float*)d_in[6];
    const float* w_geo1 = (const float*)d_in[7];
    const float* b_geo1 = (const float*)d_in[8];
    const float* w_alpha = (const float*)d_in[9];
    const float* b_alpha = (const float*)d_in[10];
    const float* w_view0 = (const float*)d_in[11];
    const float* b_view0 = (const float*)d_in[12];
    const float* w_view1 = (const float*)d_in[13];
    const float* b_view1 = (const float*)d_in[14];
    const float* w_rgb = (const float*)d_in[15];
    const float* b_rgb = (const float*)d_in[16];

    char* ws = (char*)d_ws;
    size_t off = 0;
    auto alloc = [&](size_t bytes) { void* p = ws + off; off += (bytes + 255) & ~(size_t)255; return p; };
    bf16*   latT = (bf16*)alloc((size_t)C_LAT * RESO * RESO * 2);   // 25.2 MB
    float4* V4   = (float4*)alloc((size_t)NVERT * 16);              // 110 KB
    bf16*   W0b  = (bf16*)alloc((size_t)256 * 128 * 2);
    bf16*   W1b  = (bf16*)alloc((size_t)256 * 256 * 2);
    bf16*   W2b  = (bf16*)alloc((size_t)256 * 384 * 2);
    bf16*   W3b  = (bf16*)alloc((size_t)128 * 256 * 2);

    float* out = (float*)d_out;

    hipLaunchKernelGGL(transpose_latent, dim3(1024), dim3(256), 0, stream, input_latent, latT);
    hipLaunchKernelGGL(prep, dim3(384), dim3(256), 0, stream,
                       w_geo0, w_geo1, w_view0, w_view1, smpl_verts,
                       W0b, W1b, W2b, W3b, V4);
    hipLaunchKernelGGL(mega, dim3(N_PTS / ROWS), dim3(512), 0, stream,
                       sampled_pts, V4, vts_uv, latT, view_dir,
                       W0b, b_geo0, W1b, b_geo1, W2b, b_view0, W3b, b_view1,
                       w_alpha, b_alpha, w_rgb, b_rgb, out);
}

// Round 7
// 192.923 us; speedup vs baseline: 1.2515x; 1.2515x over previous
//
#include <hip/hip_runtime.h>
#include <hip/hip_bf16.h>
#include <math.h>
#include <float.h>

#define N_PTS 16384
#define NVERT 6890
#define RESO 256
#define C_LAT 192
#define VIEW_DIM 27

#define NCHUNK 16
#define CHUNK 431   // 16*431 = 6896 >= 6890

typedef __hip_bfloat16 bf16;
typedef __bf16 bf16x8 __attribute__((ext_vector_type(8)));
typedef float f32x4 __attribute__((ext_vector_type(4)));

// swizzled LDS byte offset within a row-major bf16 tile (row stride LDB bytes).
// XOR stays inside the 16B-slot space of a row ((row&7)<<4 <= 112 < 256 <= LDB).
__device__ __forceinline__ int swz(int row, int kbyte, int LDB) {
    return row * LDB + (kbyte ^ ((row & 7) << 4));
}

// ---------------- K1: latent transpose + weight prep (fused by block range) ----------------
__global__ __launch_bounds__(256) void transpose_prep(const float* __restrict__ lat,
                                                      const float* __restrict__ w0,
                                                      const float* __restrict__ w1,
                                                      const float* __restrict__ w2,
                                                      const float* __restrict__ w3,
                                                      bf16* __restrict__ latT,
                                                      bf16* __restrict__ W0b,   // [256][128]
                                                      bf16* __restrict__ W1b,   // [256][256]
                                                      bf16* __restrict__ W2b,   // [256][384]
                                                      bf16* __restrict__ W3b) { // [128][256]
    __shared__ float tile[C_LAT][65];
    int t = threadIdx.x;
    if (blockIdx.x < 1024) {
        int b = blockIdx.x;
        int y = b >> 2;
        int x0 = (b & 3) << 6;
        #pragma unroll
        for (int i = 0; i < (C_LAT * 64) / 256; ++i) {   // 48 iters
            int e = i * 256 + t;
            int c = e >> 6, xi = e & 63;
            tile[c][xi] = lat[c * (RESO * RESO) + y * RESO + x0 + xi];
        }
        __syncthreads();
        #pragma unroll
        for (int i = 0; i < (C_LAT * 64) / 256; ++i) {
            int e = i * 256 + t;
            int xi = e / C_LAT, c = e % C_LAT;
            latT[(size_t)(y * RESO + x0 + xi) * C_LAT + c] = __float2bfloat16(tile[c][xi]);
        }
    } else {
        int i = (blockIdx.x - 1024) * 256 + t;   // 384*256 = 98304
        if (i < 256 * 128) {
            int n = i >> 7, k = i & 127;
            W0b[i] = __float2bfloat16((k < 127) ? w0[n * 127 + k] : 0.0f);
        }
        if (i < 256 * 256) W1b[i] = __float2bfloat16(w1[i]);
        if (i < 256 * 384) {
            int n = i / 384, k = i % 384;
            W2b[i] = __float2bfloat16((k < 347) ? w2[n * 347 + k] : 0.0f);
        }
        if (i < 128 * 256) W3b[i] = __float2bfloat16(w3[i]);
    }
}

// ---------------- K2: nearest-neighbor partial argmin (round-1 proven, exact ref arithmetic) ----------------
__global__ __launch_bounds__(256) void nn_partial(const float* __restrict__ P,
                                                  const float* __restrict__ V,
                                                  float* __restrict__ pd2,
                                                  int* __restrict__ pidx) {
    __shared__ float4 vs[CHUNK];
    int t = threadIdx.x;
    int pc = blockIdx.x;   // 0..63
    int vc = blockIdx.y;   // 0..15
    int vstart = vc * CHUNK;
    int count = min(CHUNK, NVERT - vstart);
    for (int i = t; i < count; i += 256) {
        int g = vstart + i;
        float x = V[g * 3 + 0], y = V[g * 3 + 1], z = V[g * 3 + 2];
        float v2 = __fadd_rn(__fadd_rn(__fmul_rn(x, x), __fmul_rn(y, y)), __fmul_rn(z, z));
        vs[i] = make_float4(x, y, z, v2);
    }
    __syncthreads();
    int n = pc * 256 + t;
    float px = P[n * 3 + 0], py = P[n * 3 + 1], pz = P[n * 3 + 2];
    float p2 = __fadd_rn(__fadd_rn(__fmul_rn(px, px), __fmul_rn(py, py)), __fmul_rn(pz, pz));
    float best = FLT_MAX;
    int bi = 0;
    for (int v = 0; v < count; ++v) {
        float4 q = vs[v];
        float dot = fmaf(pz, q.z, fmaf(py, q.y, __fmul_rn(px, q.x)));
        float d2 = __fsub_rn(__fadd_rn(p2, q.w), __fmul_rn(2.0f, dot));
        if (d2 < best) { best = d2; bi = vstart + v; }
    }
    pd2[n * NCHUNK + vc] = best;
    pidx[n * NCHUNK + vc] = bi;
}

// ---------------- K3: reduce partials + bilinear + embed -> X1[ N][128], Xe[N][128] ----------------
// X1: [fused 0..63 | h,u,v,sin30,cos30 64..126 | 0] ; Xe: [view 0..26 | fused 27..90 | 0 91..127]
__global__ __launch_bounds__(256) void sample_embed(const float* __restrict__ pd2,
                                                    const int* __restrict__ pidx,
                                                    const float* __restrict__ vts_uv,
                                                    const bf16* __restrict__ latT,
                                                    const float* __restrict__ view_dir,
                                                    bf16* __restrict__ X1,
                                                    bf16* __restrict__ Xe) {
    int t = threadIdx.x;
    int lane = t & 63, w = t >> 6;
    int n = blockIdx.x * 4 + w;
    float best = FLT_MAX;
    int bi = 0;
    #pragma unroll
    for (int c = 0; c < NCHUNK; ++c) {     // ascending chunk order + strict < = numpy argmin
        float d = pd2[n * NCHUNK + c];
        int ix = pidx[n * NCHUNK + c];
        if (d < best) { best = d; bi = ix; }
    }
    float u = vts_uv[bi * 2 + 0], vv = vts_uv[bi * 2 + 1];
    float h = __fsqrt_rn(fmaxf(best, 1e-12f));
    float hn = __fmul_rn(__fadd_rn(__fdiv_rn(h, 0.1f), 1.0f), 0.5f);

    float fsum = 0.0f;
    #pragma unroll
    for (int p = 0; p < 3; ++p) {
        float xc = (p == 2) ? hn : u;
        float yc = (p == 1) ? hn : vv;
        float x = fminf(fmaxf(xc, 0.0f), 1.0f) * 255.0f;
        float y = fminf(fmaxf(yc, 0.0f), 1.0f) * 255.0f;
        float x0 = floorf(x), y0 = floorf(y);
        float wx = x - x0, wy = y - y0;
        int x0i = min(max((int)x0, 0), 255), y0i = min(max((int)y0, 0), 255);
        int x1i = min(x0i + 1, 255), y1i = min(y0i + 1, 255);
        int co = p * 64 + lane;
        float f00 = __bfloat162float(latT[(size_t)(y0i * 256 + x0i) * C_LAT + co]);
        float f01 = __bfloat162float(latT[(size_t)(y0i * 256 + x1i) * C_LAT + co]);
        float f10 = __bfloat162float(latT[(size_t)(y1i * 256 + x0i) * C_LAT + co]);
        float f11 = __bfloat162float(latT[(size_t)(y1i * 256 + x1i) * C_LAT + co]);
        fsum += f00 * (1 - wx) * (1 - wy) + f01 * wx * (1 - wy) + f10 * (1 - wx) * wy + f11 * wx * wy;
    }
    bf16 fb = __float2bfloat16(fsum / 3.0f);
    X1[(size_t)n * 128 + lane] = fb;
    Xe[(size_t)n * 128 + 27 + lane] = fb;

    if (lane < 63) {
        float val;
        if (lane < 3) {
            val = (lane == 0) ? h : ((lane == 1) ? u : vv);
        } else {
            int e = lane - 3;
            if (e < 30) {
                int d = e / 10, k = e % 10;
                float pv = (d == 0) ? h : ((d == 1) ? u : vv);
                val = sinf(pv * (float)(1 << k));
            } else {
                e -= 30;
                int d = e / 10, k = e % 10;
                float pv = (d == 0) ? h : ((d == 1) ? u : vv);
                val = cosf(pv * (float)(1 << k));
            }
        }
        X1[(size_t)n * 128 + 64 + lane] = __float2bfloat16(val);
    } else {
        X1[(size_t)n * 128 + 127] = __float2bfloat16(0.0f);
    }
    if (lane < VIEW_DIM)
        Xe[(size_t)n * 128 + lane] = __float2bfloat16(view_dir[(size_t)n * VIEW_DIM + lane]);
    if (lane < 37)
        Xe[(size_t)n * 128 + 91 + lane] = __float2bfloat16(0.0f);
}

// ---------------- K4: fused 4-layer MLP + heads, activations LDS-resident ----------------
__global__ __launch_bounds__(512) void mlp_fused(const bf16* __restrict__ X1g,
                                                 const bf16* __restrict__ Xeg,
                                                 const bf16* __restrict__ W0, const float* __restrict__ b0,
                                                 const bf16* __restrict__ W1, const float* __restrict__ b1,
                                                 const bf16* __restrict__ W2, const float* __restrict__ b2,
                                                 const bf16* __restrict__ W3, const float* __restrict__ b3,
                                                 const float* __restrict__ w_alpha, const float* __restrict__ b_alpha,
                                                 const float* __restrict__ w_rgb, const float* __restrict__ b_rgb,
                                                 float* __restrict__ out) {
    __shared__ __align__(16) char bufA[64 * 512];   // X1 (LDB256) -> net1 (LDB512)
    __shared__ __align__(16) char bufB[64 * 512];   // A1 / A3 (LDB512)
    __shared__ __align__(16) char bufC[64 * 256];   // Xe (LDB256) -> A4 (LDB256)

    const int t = threadIdx.x;
    const int lane = t & 63;
    const int w = t >> 6;
    const int lr = lane & 15, lg = lane >> 4;
    const int n0 = blockIdx.x * 64;

    // stage X1 -> bufA, Xe -> bufC (pre-swizzled ds_write, 16B chunks)
    #pragma unroll
    for (int i = 0; i < 2; ++i) {
        int c = i * 512 + t;             // 0..1023
        int row = c >> 4, sl = c & 15;
        ulonglong2 v = *(const ulonglong2*)(X1g + (size_t)(n0 + row) * 128 + sl * 8);
        *(ulonglong2*)(bufA + swz(row, sl * 16, 256)) = v;
    }
    {
        int c = t;                        // 512 = 64 rows x 8 chunks? no: 64x16 = 1024 -> 2 rounds
        int row = c >> 4, sl = c & 15;
        ulonglong2 v = *(const ulonglong2*)(Xeg + (size_t)(n0 + row) * 128 + sl * 8);
        *(ulonglong2*)(bufC + swz(row, sl * 16, 256)) = v;
        c = 512 + t;
        row = c >> 4; sl = c & 15;
        v = *(const ulonglong2*)(Xeg + (size_t)(n0 + row) * 128 + sl * 8);
        *(ulonglong2*)(bufC + swz(row, sl * 16, 256)) = v;
    }
    __syncthreads();

    const int wm = w >> 2, wn = w & 3;

    // ---- L0: A=bufA(LDB256, K=128)  B=W0[256][128] -> relu -> bufB(LDB512) ----
    {
        f32x4 acc[2][4] = {};
        #pragma unroll 2
        for (int ks = 0; ks < 4; ++ks) {
            int kt = ks * 32;
            bf16x8 a[2], b[4];
            #pragma unroll
            for (int m = 0; m < 2; ++m) {
                int row = wm * 32 + m * 16 + lr;
                a[m] = *(const bf16x8*)(bufA + swz(row, (kt + lg * 8) * 2, 256));
            }
            #pragma unroll
            for (int nn = 0; nn < 4; ++nn) {
                int col = wn * 64 + nn * 16 + lr;
                b[nn] = *(const bf16x8*)(W0 + (size_t)col * 128 + kt + lg * 8);
            }
            #pragma unroll
            for (int m = 0; m < 2; ++m)
                #pragma unroll
                for (int nn = 0; nn < 4; ++nn)
                    acc[m][nn] = __builtin_amdgcn_mfma_f32_16x16x32_bf16(a[m], b[nn], acc[m][nn], 0, 0, 0);
        }
        #pragma unroll
        for (int nn = 0; nn < 4; ++nn) {
            int col = wn * 64 + nn * 16 + lr;
            float bv = b0[col];
            #pragma unroll
            for (int m = 0; m < 2; ++m)
                #pragma unroll
                for (int j = 0; j < 4; ++j) {
                    int row = wm * 32 + m * 16 + lg * 4 + j;
                    *(bf16*)(bufB + swz(row, col * 2, 512)) =
                        __float2bfloat16(fmaxf(acc[m][nn][j] + bv, 0.0f));
                }
        }
    }
    __syncthreads();

    // ---- L1: A=bufB(512, K=256)  B=W1[256][256] -> relu -> bufA(512) (net1) ----
    {
        f32x4 acc[2][4] = {};
        #pragma unroll 2
        for (int ks = 0; ks < 8; ++ks) {
            int kt = ks * 32;
            bf16x8 a[2], b[4];
            #pragma unroll
            for (int m = 0; m < 2; ++m) {
                int row = wm * 32 + m * 16 + lr;
                a[m] = *(const bf16x8*)(bufB + swz(row, (kt + lg * 8) * 2, 512));
            }
            #pragma unroll
            for (int nn = 0; nn < 4; ++nn) {
                int col = wn * 64 + nn * 16 + lr;
                b[nn] = *(const bf16x8*)(W1 + (size_t)col * 256 + kt + lg * 8);
            }
            #pragma unroll
            for (int m = 0; m < 2; ++m)
                #pragma unroll
                for (int nn = 0; nn < 4; ++nn)
                    acc[m][nn] = __builtin_amdgcn_mfma_f32_16x16x32_bf16(a[m], b[nn], acc[m][nn], 0, 0, 0);
        }
        #pragma unroll
        for (int nn = 0; nn < 4; ++nn) {
            int col = wn * 64 + nn * 16 + lr;
            float bv = b1[col];
            #pragma unroll
            for (int m = 0; m < 2; ++m)
                #pragma unroll
                for (int j = 0; j < 4; ++j) {
                    int row = wm * 32 + m * 16 + lg * 4 + j;
                    *(bf16*)(bufA + swz(row, col * 2, 512)) =
                        __float2bfloat16(fmaxf(acc[m][nn][j] + bv, 0.0f));
                }
        }
    }
    __syncthreads();

    // ---- L2: A=[bufA(512) K0..255 | bufC(256) K256..383]  B=W2[256][384] -> relu -> bufB(512) ----
    {
        f32x4 acc[2][4] = {};
        #pragma unroll 2
        for (int ks = 0; ks < 12; ++ks) {
            int kt = ks * 32;
            bf16x8 a[2], b[4];
            #pragma unroll
            for (int m = 0; m < 2; ++m) {
                int row = wm * 32 + m * 16 + lr;
                if (kt < 256)
                    a[m] = *(const bf16x8*)(bufA + swz(row, (kt + lg * 8) * 2, 512));
                else
                    a[m] = *(const bf16x8*)(bufC + swz(row, (kt - 256 + lg * 8) * 2, 256));
            }
            #pragma unroll
            for (int nn = 0; nn < 4; ++nn) {
                int col = wn * 64 + nn * 16 + lr;
                b[nn] = *(const bf16x8*)(W2 + (size_t)col * 384 + kt + lg * 8);
            }
            #pragma unroll
            for (int m = 0; m < 2; ++m)
                #pragma unroll
                for (int nn = 0; nn < 4; ++nn)
                    acc[m][nn] = __builtin_amdgcn_mfma_f32_16x16x32_bf16(a[m], b[nn], acc[m][nn], 0, 0, 0);
        }
        #pragma unroll
        for (int nn = 0; nn < 4; ++nn) {
            int col = wn * 64 + nn * 16 + lr;
            float bv = b2[col];
            #pragma unroll
            for (int m = 0; m < 2; ++m)
                #pragma unroll
                for (int j = 0; j < 4; ++j) {
                    int row = wm * 32 + m * 16 + lg * 4 + j;
                    *(bf16*)(bufB + swz(row, col * 2, 512)) =
                        __float2bfloat16(fmaxf(acc[m][nn][j] + bv, 0.0f));
                }
        }
    }
    __syncthreads();

    // ---- L3: A=bufB(512, K=256)  B=W3[128][256] -> relu -> bufC(256) (A4) ----
    {
        f32x4 acc[2][2] = {};
        #pragma unroll 2
        for (int ks = 0; ks < 8; ++ks) {
            int kt = ks * 32;
            bf16x8 a[2], b[2];
            #pragma unroll
            for (int m = 0; m < 2; ++m) {
                int row = wm * 32 + m * 16 + lr;
                a[m] = *(const bf16x8*)(bufB + swz(row, (kt + lg * 8) * 2, 512));
            }
            #pragma unroll
            for (int nn = 0; nn < 2; ++nn) {
                int col = wn * 32 + nn * 16 + lr;
                b[nn] = *(const bf16x8*)(W3 + (size_t)col * 256 + kt + lg * 8);
            }
            #pragma unroll
            for (int m = 0; m < 2; ++m)
                #pragma unroll
                for (int nn = 0; nn < 2; ++nn)
                    acc[m][nn] = __builtin_amdgcn_mfma_f32_16x16x32_bf16(a[m], b[nn], acc[m][nn], 0, 0, 0);
        }
        #pragma unroll
        for (int nn = 0; nn < 2; ++nn) {
            int col = wn * 32 + nn * 16 + lr;
            float bv = b3[col];
            #pragma unroll
            for (int m = 0; m < 2; ++m)
                #pragma unroll
                for (int j = 0; j < 4; ++j) {
                    int row = wm * 32 + m * 16 + lg * 4 + j;
                    *(bf16*)(bufC + swz(row, col * 2, 256)) =
                        __float2bfloat16(fmaxf(acc[m][nn][j] + bv, 0.0f));
                }
        }
    }
    __syncthreads();

    // ---- Heads: alpha = w_alpha . net1(bufA) ; rgb = w_rgb . A4(bufC) ----
    {
        int p = t >> 3, g = t & 7;
        float sa = 0.0f;
        #pragma unroll
        for (int c0 = 0; c0 < 32; ++c0) {
            int col = g * 32 + c0;
            float x = __bfloat162float(*(const bf16*)(bufA + swz(p, col * 2, 512)));
            sa = fmaf(x, w_alpha[col], sa);
        }
        float sr = 0.0f, sg = 0.0f, sb = 0.0f;
        #pragma unroll
        for (int c0 = 0; c0 < 16; ++c0) {
            int col = g * 16 + c0;
            float x = __bfloat162float(*(const bf16*)(bufC + swz(p, col * 2, 256)));
            sr = fmaf(x, w_rgb[0 * 128 + col], sr);
            sg = fmaf(x, w_rgb[1 * 128 + col], sg);
            sb = fmaf(x, w_rgb[2 * 128 + col], sb);
        }
        #pragma unroll
        for (int off = 4; off; off >>= 1) {
            sa += __shfl_xor(sa, off, 64);
            sr += __shfl_xor(sr, off, 64);
            sg += __shfl_xor(sg, off, 64);
            sb += __shfl_xor(sb, off, 64);
        }
        if (g == 0) {
            float4 o = make_float4(sa + b_alpha[0], sr + b_rgb[0], sg + b_rgb[1], sb + b_rgb[2]);
            *(float4*)(out + (size_t)(n0 + p) * 4) = o;
        }
    }
}

extern "C" void kernel_launch(void* const* d_in, const int* in_sizes, int n_in,
                              void* d_out, int out_size, void* d_ws, size_t ws_size,
                              hipStream_t stream) {
    (void)in_sizes; (void)n_in; (void)out_size; (void)ws_size;
    const float* sampled_pts  = (const float*)d_in[0];
    const float* smpl_verts   = (const float*)d_in[1];
    const float* view_dir     = (const float*)d_in[2];
    const float* input_latent = (const float*)d_in[3];
    const float* vts_uv       = (const float*)d_in[4];
    const float* w_geo0 = (const float*)d_in[5];
    const float* b_geo0 = (const float*)d_in[6];
    const float* w_geo1 = (const float*)d_in[7];
    const float* b_geo1 = (const float*)d_in[8];
    const float* w_alpha = (const float*)d_in[9];
    const float* b_alpha = (const float*)d_in[10];
    const float* w_view0 = (const float*)d_in[11];
    const float* b_view0 = (const float*)d_in[12];
    const float* w_view1 = (const float*)d_in[13];
    const float* b_view1 = (const float*)d_in[14];
    const float* w_rgb = (const float*)d_in[15];
    const float* b_rgb = (const float*)d_in[16];

    char* ws = (char*)d_ws;
    size_t off = 0;
    auto alloc = [&](size_t bytes) { void* p = ws + off; off += (bytes + 255) & ~(size_t)255; return p; };
    bf16*  latT = (bf16*)alloc((size_t)C_LAT * RESO * RESO * 2);   // 25.2 MB
    float* pd2  = (float*)alloc((size_t)N_PTS * NCHUNK * 4);       // 1 MB
    int*   pidx = (int*)alloc((size_t)N_PTS * NCHUNK * 4);         // 1 MB
    bf16*  X1   = (bf16*)alloc((size_t)N_PTS * 128 * 2);           // 4.2 MB
    bf16*  Xe   = (bf16*)alloc((size_t)N_PTS * 128 * 2);           // 4.2 MB
    bf16*  W0b  = (bf16*)alloc((size_t)256 * 128 * 2);
    bf16*  W1b  = (bf16*)alloc((size_t)256 * 256 * 2);
    bf16*  W2b  = (bf16*)alloc((size_t)256 * 384 * 2);
    bf16*  W3b  = (bf16*)alloc((size_t)128 * 256 * 2);

    float* out = (float*)d_out;

    hipLaunchKernelGGL(nn_partial, dim3(64, 16), dim3(256), 0, stream,
                       sampled_pts, smpl_verts, pd2, pidx);
    hipLaunchKernelGGL(transpose_prep, dim3(1408), dim3(256), 0, stream,
                       input_latent, w_geo0, w_geo1, w_view0, w_view1,
                       latT, W0b, W1b, W2b, W3b);
    hipLaunchKernelGGL(sample_embed, dim3(4096), dim3(256), 0, stream,
                       pd2, pidx, vts_uv, latT, view_dir, X1, Xe);
    hipLaunchKernelGGL(mlp_fused, dim3(N_PTS / 64), dim3(512), 0, stream,
                       X1, Xe, W0b, b_geo0, W1b, b_geo1, W2b, b_view0, W3b, b_view1,
                       w_alpha, b_alpha, w_rgb, b_rgb, out);
}

// Round 8
// 188.629 us; speedup vs baseline: 1.2800x; 1.0228x over previous
//
#include <hip/hip_runtime.h>
#include <hip/hip_bf16.h>
#include <math.h>
#include <float.h>

#define N_PTS 16384
#define NVERT 6890
#define RESO 256
#define C_LAT 192
#define VIEW_DIM 27

#define NCHUNK 16
#define CHUNK 431         // 16*431 = 6896 >= 6890

#define NB_T 2048         // transpose blocks (32-col tiles)
#define NB_N 1024         // nn blocks (64 pt-chunks x 16 v-chunks)
#define NB_W 384          // weight-prep blocks

typedef __hip_bfloat16 bf16;
typedef __bf16 bf16x8 __attribute__((ext_vector_type(8)));
typedef float f32x4 __attribute__((ext_vector_type(4)));

// swizzled LDS byte offset within a row-major bf16 tile (row stride LDB bytes).
__device__ __forceinline__ int swz(int row, int kbyte, int LDB) {
    return row * LDB + (kbyte ^ ((row & 7) << 4));
}

// ---------------- K1: transpose (HBM-bound) + NN argmin (VALU-bound) + weight prep, overlapped ----------------
__global__ __launch_bounds__(256) void fused_pre(const float* __restrict__ lat,
                                                 const float* __restrict__ P,
                                                 const float* __restrict__ V,
                                                 const float* __restrict__ w0,
                                                 const float* __restrict__ w1,
                                                 const float* __restrict__ w2,
                                                 const float* __restrict__ w3,
                                                 bf16* __restrict__ latT,
                                                 float* __restrict__ pd2,
                                                 int* __restrict__ pidx,
                                                 bf16* __restrict__ W0b,   // [256][128]
                                                 bf16* __restrict__ W1b,   // [256][256]
                                                 bf16* __restrict__ W2b,   // [256][384]
                                                 bf16* __restrict__ W3b) { // [128][256]
    __shared__ __align__(16) char sm[C_LAT * 33 * 4];   // 25344 B (union: tile / vs)
    int t = threadIdx.x;
    int b = blockIdx.x;
    if (b < NB_T) {
        // ---- latent transpose: [C][H][W] fp32 -> [H][W][C] bf16, 32-col tiles ----
        float (*tile)[33] = (float (*)[33])sm;
        int y = b >> 3;
        int x0 = (b & 7) << 5;
        #pragma unroll
        for (int i = 0; i < (C_LAT * 32) / 256; ++i) {   // 24 iters
            int e = i * 256 + t;
            int c = e >> 5, xi = e & 31;
            tile[c][xi] = lat[c * (RESO * RESO) + y * RESO + x0 + xi];
        }
        __syncthreads();
        #pragma unroll
        for (int i = 0; i < (C_LAT * 32) / 256; ++i) {
            int e = i * 256 + t;
            int xi = e / C_LAT, c = e % C_LAT;
            latT[(size_t)(y * RESO + x0 + xi) * C_LAT + c] = __float2bfloat16(tile[c][xi]);
        }
    } else if (b < NB_T + NB_N) {
        // ---- NN partial argmin (exact ref arithmetic, strict < in ascending v) ----
        float4* vs = (float4*)sm;
        int bb = b - NB_T;
        int pc = bb >> 4;    // 0..63
        int vc = bb & 15;    // 0..15
        int vstart = vc * CHUNK;
        int count = min(CHUNK, NVERT - vstart);
        for (int i = t; i < count; i += 256) {
            int g = vstart + i;
            float x = V[g * 3 + 0], y = V[g * 3 + 1], z = V[g * 3 + 2];
            float v2 = __fadd_rn(__fadd_rn(__fmul_rn(x, x), __fmul_rn(y, y)), __fmul_rn(z, z));
            vs[i] = make_float4(x, y, z, v2);
        }
        __syncthreads();
        int n = pc * 256 + t;
        float px = P[n * 3 + 0], py = P[n * 3 + 1], pz = P[n * 3 + 2];
        float p2 = __fadd_rn(__fadd_rn(__fmul_rn(px, px), __fmul_rn(py, py)), __fmul_rn(pz, pz));
        float best = FLT_MAX;
        int bi = 0;
        for (int v = 0; v < count; ++v) {
            float4 q = vs[v];
            float dot = fmaf(pz, q.z, fmaf(py, q.y, __fmul_rn(px, q.x)));
            float d2 = __fsub_rn(__fadd_rn(p2, q.w), __fmul_rn(2.0f, dot));
            if (d2 < best) { best = d2; bi = vstart + v; }
        }
        pd2[n * NCHUNK + vc] = best;
        pidx[n * NCHUNK + vc] = bi;
    } else {
        // ---- weight conversion/padding to bf16 ----
        int i = (b - NB_T - NB_N) * 256 + t;   // < 98304
        if (i < 256 * 128) {
            int n = i >> 7, k = i & 127;
            W0b[i] = __float2bfloat16((k < 127) ? w0[n * 127 + k] : 0.0f);
        }
        if (i < 256 * 256) W1b[i] = __float2bfloat16(w1[i]);
        if (i < 256 * 384) {
            int n = i / 384, k = i % 384;
            W2b[i] = __float2bfloat16((k < 347) ? w2[n * 347 + k] : 0.0f);
        }
        if (i < 128 * 256) W3b[i] = __float2bfloat16(w3[i]);
    }
}

// ---------------- K2: reduce + bilinear + embed + 4-layer MLP + heads (64 pts/block) ----------------
__global__ __launch_bounds__(512) void mega_lite(const float* __restrict__ pd2,
                                                 const int* __restrict__ pidx,
                                                 const float* __restrict__ vts_uv,
                                                 const bf16* __restrict__ latT,
                                                 const float* __restrict__ view_dir,
                                                 const bf16* __restrict__ W0, const float* __restrict__ b0,
                                                 const bf16* __restrict__ W1, const float* __restrict__ b1,
                                                 const bf16* __restrict__ W2, const float* __restrict__ b2,
                                                 const bf16* __restrict__ W3, const float* __restrict__ b3,
                                                 const float* __restrict__ w_alpha, const float* __restrict__ b_alpha,
                                                 const float* __restrict__ w_rgb, const float* __restrict__ b_rgb,
                                                 float* __restrict__ out) {
    __shared__ __align__(16) char bufA[64 * 512];   // X1 (LDB256) -> net1 (LDB512)
    __shared__ __align__(16) char bufB[64 * 512];   // A1 / A3 (LDB512)
    __shared__ __align__(16) char bufC[64 * 256];   // Xe (LDB256) -> A4 (LDB256)
    __shared__ float hunv[3][64];

    const int t = threadIdx.x;
    const int lane = t & 63;
    const int w = t >> 6;
    const int lr = lane & 15, lg = lane >> 4;
    const int n0 = blockIdx.x * 64;

    // ---- Phase A: chunk-reduce argmin (8 threads/pt, lexicographic (d,idx) min) ----
    {
        int p = t >> 3, g = t & 7;
        int n = n0 + p;
        float d0 = pd2[n * NCHUNK + g];
        int i0 = pidx[n * NCHUNK + g];
        float d1 = pd2[n * NCHUNK + 8 + g];
        int i1 = pidx[n * NCHUNK + 8 + g];
        if (d1 < d0 || (d1 == d0 && i1 < i0)) { d0 = d1; i0 = i1; }
        #pragma unroll
        for (int off = 1; off < 8; off <<= 1) {
            float dd = __shfl_xor(d0, off, 8);
            int ii = __shfl_xor(i0, off, 8);
            if (dd < d0 || (dd == d0 && ii < i0)) { d0 = dd; i0 = ii; }
        }
        if (g == 0) {
            hunv[0][p] = __fsqrt_rn(fmaxf(d0, 1e-12f));
            hunv[1][p] = vts_uv[i0 * 2 + 0];
            hunv[2][p] = vts_uv[i0 * 2 + 1];
        }
    }
    __syncthreads();

    // ---- Phase B1: bilinear fusion (wave w -> points w*8..w*8+7; lane = channel) ----
    {
        #pragma unroll
        for (int pp = 0; pp < 8; ++pp) {
            int p = w * 8 + pp;
            float h = hunv[0][p], u = hunv[1][p], vv = hunv[2][p];
            float hn = __fmul_rn(__fadd_rn(__fdiv_rn(h, 0.1f), 1.0f), 0.5f);
            float fsum = 0.0f;
            #pragma unroll
            for (int pl = 0; pl < 3; ++pl) {
                float xc = (pl == 2) ? hn : u;
                float yc = (pl == 1) ? hn : vv;
                float x = fminf(fmaxf(xc, 0.0f), 1.0f) * 255.0f;
                float y = fminf(fmaxf(yc, 0.0f), 1.0f) * 255.0f;
                float x0 = floorf(x), y0 = floorf(y);
                float wx = x - x0, wy = y - y0;
                int x0i = min(max((int)x0, 0), 255), y0i = min(max((int)y0, 0), 255);
                int x1i = min(x0i + 1, 255), y1i = min(y0i + 1, 255);
                int co = pl * 64 + lane;
                float f00 = __bfloat162float(latT[(size_t)(y0i * 256 + x0i) * C_LAT + co]);
                float f01 = __bfloat162float(latT[(size_t)(y0i * 256 + x1i) * C_LAT + co]);
                float f10 = __bfloat162float(latT[(size_t)(y1i * 256 + x0i) * C_LAT + co]);
                float f11 = __bfloat162float(latT[(size_t)(y1i * 256 + x1i) * C_LAT + co]);
                fsum += f00 * (1 - wx) * (1 - wy) + f01 * wx * (1 - wy) + f10 * (1 - wx) * wy + f11 * wx * wy;
            }
            bf16 fb = __float2bfloat16(fsum / 3.0f);
            *(bf16*)(bufA + swz(p, lane * 2, 256)) = fb;             // X1 cols 0..63
            *(bf16*)(bufC + swz(p, (27 + lane) * 2, 256)) = fb;      // Xe cols 27..90
        }
    }

    // ---- Phase B2: embed + view_dir + zero pads (thread p=t>>3, i=t&7) ----
    {
        int p = t >> 3, i = t & 7;
        float h = hunv[0][p], u = hunv[1][p], vv = hunv[2][p];
        #pragma unroll
        for (int r = 0; r < 8; ++r) {
            int j = i + r * 8;          // 0..63
            float val;
            if (j == 63) {
                val = 0.0f;             // X1 col 127 pad
            } else if (j < 3) {
                val = (j == 0) ? h : ((j == 1) ? u : vv);
            } else if (j < 33) {
                int e = j - 3;
                int d = e / 10, k = e % 10;
                float pv = (d == 0) ? h : ((d == 1) ? u : vv);
                val = sinf(pv * (float)(1 << k));
            } else {
                int e = j - 33;
                int d = e / 10, k = e % 10;
                float pv = (d == 0) ? h : ((d == 1) ? u : vv);
                val = cosf(pv * (float)(1 << k));
            }
            *(bf16*)(bufA + swz(p, (64 + j) * 2, 256)) = __float2bfloat16(val);
        }
        #pragma unroll
        for (int r = 0; r < 4; ++r) {
            int c = i + r * 8;          // 0..31
            if (c < VIEW_DIM)
                *(bf16*)(bufC + swz(p, c * 2, 256)) =
                    __float2bfloat16(view_dir[(size_t)(n0 + p) * VIEW_DIM + c]);
        }
        #pragma unroll
        for (int r = 0; r < 5; ++r) {
            int c = 91 + i + r * 8;     // zero Xe cols 91..127
            if (c < 128)
                *(bf16*)(bufC + swz(p, c * 2, 256)) = __float2bfloat16(0.0f);
        }
    }
    __syncthreads();

    const int wm = w >> 2, wn = w & 3;

    // ---- L0: A=bufA(LDB256, K=128)  B=W0[256][128] -> relu -> bufB(LDB512) ----
    {
        f32x4 acc[2][4] = {};
        #pragma unroll 2
        for (int ks = 0; ks < 4; ++ks) {
            int kt = ks * 32;
            bf16x8 a[2], b[4];
            #pragma unroll
            for (int m = 0; m < 2; ++m) {
                int row = wm * 32 + m * 16 + lr;
                a[m] = *(const bf16x8*)(bufA + swz(row, (kt + lg * 8) * 2, 256));
            }
            #pragma unroll
            for (int nn = 0; nn < 4; ++nn) {
                int col = wn * 64 + nn * 16 + lr;
                b[nn] = *(const bf16x8*)(W0 + (size_t)col * 128 + kt + lg * 8);
            }
            #pragma unroll
            for (int m = 0; m < 2; ++m)
                #pragma unroll
                for (int nn = 0; nn < 4; ++nn)
                    acc[m][nn] = __builtin_amdgcn_mfma_f32_16x16x32_bf16(a[m], b[nn], acc[m][nn], 0, 0, 0);
        }
        #pragma unroll
        for (int nn = 0; nn < 4; ++nn) {
            int col = wn * 64 + nn * 16 + lr;
            float bv = b0[col];
            #pragma unroll
            for (int m = 0; m < 2; ++m)
                #pragma unroll
                for (int j = 0; j < 4; ++j) {
                    int row = wm * 32 + m * 16 + lg * 4 + j;
                    *(bf16*)(bufB + swz(row, col * 2, 512)) =
                        __float2bfloat16(fmaxf(acc[m][nn][j] + bv, 0.0f));
                }
        }
    }
    __syncthreads();

    // ---- L1: A=bufB(512, K=256)  B=W1[256][256] -> relu -> bufA(512) (net1) ----
    {
        f32x4 acc[2][4] = {};
        #pragma unroll 2
        for (int ks = 0; ks < 8; ++ks) {
            int kt = ks * 32;
            bf16x8 a[2], b[4];
            #pragma unroll
            for (int m = 0; m < 2; ++m) {
                int row = wm * 32 + m * 16 + lr;
                a[m] = *(const bf16x8*)(bufB + swz(row, (kt + lg * 8) * 2, 512));
            }
            #pragma unroll
            for (int nn = 0; nn < 4; ++nn) {
                int col = wn * 64 + nn * 16 + lr;
                b[nn] = *(const bf16x8*)(W1 + (size_t)col * 256 + kt + lg * 8);
            }
            #pragma unroll
            for (int m = 0; m < 2; ++m)
                #pragma unroll
                for (int nn = 0; nn < 4; ++nn)
                    acc[m][nn] = __builtin_amdgcn_mfma_f32_16x16x32_bf16(a[m], b[nn], acc[m][nn], 0, 0, 0);
        }
        #pragma unroll
        for (int nn = 0; nn < 4; ++nn) {
            int col = wn * 64 + nn * 16 + lr;
            float bv = b1[col];
            #pragma unroll
            for (int m = 0; m < 2; ++m)
                #pragma unroll
                for (int j = 0; j < 4; ++j) {
                    int row = wm * 32 + m * 16 + lg * 4 + j;
                    *(bf16*)(bufA + swz(row, col * 2, 512)) =
                        __float2bfloat16(fmaxf(acc[m][nn][j] + bv, 0.0f));
                }
        }
    }
    __syncthreads();

    // ---- L2: A=[bufA(512) K0..255 | bufC(256) K256..383]  B=W2[256][384] -> relu -> bufB(512) ----
    {
        f32x4 acc[2][4] = {};
        #pragma unroll 2
        for (int ks = 0; ks < 12; ++ks) {
            int kt = ks * 32;
            bf16x8 a[2], b[4];
            #pragma unroll
            for (int m = 0; m < 2; ++m) {
                int row = wm * 32 + m * 16 + lr;
                if (kt < 256)
                    a[m] = *(const bf16x8*)(bufA + swz(row, (kt + lg * 8) * 2, 512));
                else
                    a[m] = *(const bf16x8*)(bufC + swz(row, (kt - 256 + lg * 8) * 2, 256));
            }
            #pragma unroll
            for (int nn = 0; nn < 4; ++nn) {
                int col = wn * 64 + nn * 16 + lr;
                b[nn] = *(const bf16x8*)(W2 + (size_t)col * 384 + kt + lg * 8);
            }
            #pragma unroll
            for (int m = 0; m < 2; ++m)
                #pragma unroll
                for (int nn = 0; nn < 4; ++nn)
                    acc[m][nn] = __builtin_amdgcn_mfma_f32_16x16x32_bf16(a[m], b[nn], acc[m][nn], 0, 0, 0);
        }
        #pragma unroll
        for (int nn = 0; nn < 4; ++nn) {
            int col = wn * 64 + nn * 16 + lr;
            float bv = b2[col];
            #pragma unroll
            for (int m = 0; m < 2; ++m)
                #pragma unroll
                for (int j = 0; j < 4; ++j) {
                    int row = wm * 32 + m * 16 + lg * 4 + j;
                    *(bf16*)(bufB + swz(row, col * 2, 512)) =
                        __float2bfloat16(fmaxf(acc[m][nn][j] + bv, 0.0f));
                }
        }
    }
    __syncthreads();

    // ---- L3: A=bufB(512, K=256)  B=W3[128][256] -> relu -> bufC(256) (A4) ----
    {
        f32x4 acc[2][2] = {};
        #pragma unroll 2
        for (int ks = 0; ks < 8; ++ks) {
            int kt = ks * 32;
            bf16x8 a[2], b[2];
            #pragma unroll
            for (int m = 0; m < 2; ++m) {
                int row = wm * 32 + m * 16 + lr;
                a[m] = *(const bf16x8*)(bufB + swz(row, (kt + lg * 8) * 2, 512));
            }
            #pragma unroll
            for (int nn = 0; nn < 2; ++nn) {
                int col = wn * 32 + nn * 16 + lr;
                b[nn] = *(const bf16x8*)(W3 + (size_t)col * 256 + kt + lg * 8);
            }
            #pragma unroll
            for (int m = 0; m < 2; ++m)
                #pragma unroll
                for (int nn = 0; nn < 2; ++nn)
                    acc[m][nn] = __builtin_amdgcn_mfma_f32_16x16x32_bf16(a[m], b[nn], acc[m][nn], 0, 0, 0);
        }
        #pragma unroll
        for (int nn = 0; nn < 2; ++nn) {
            int col = wn * 32 + nn * 16 + lr;
            float bv = b3[col];
            #pragma unroll
            for (int m = 0; m < 2; ++m)
                #pragma unroll
                for (int j = 0; j < 4; ++j) {
                    int row = wm * 32 + m * 16 + lg * 4 + j;
                    *(bf16*)(bufC + swz(row, col * 2, 256)) =
                        __float2bfloat16(fmaxf(acc[m][nn][j] + bv, 0.0f));
                }
        }
    }
    __syncthreads();

    // ---- Heads: alpha = w_alpha . net1(bufA) ; rgb = w_rgb . A4(bufC) ----
    {
        int p = t >> 3, g = t & 7;
        float sa = 0.0f;
        #pragma unroll
        for (int c0 = 0; c0 < 32; ++c0) {
            int col = g * 32 + c0;
            float x = __bfloat162float(*(const bf16*)(bufA + swz(p, col * 2, 512)));
            sa = fmaf(x, w_alpha[col], sa);
        }
        float sr = 0.0f, sg = 0.0f, sb = 0.0f;
        #pragma unroll
        for (int c0 = 0; c0 < 16; ++c0) {
            int col = g * 16 + c0;
            float x = __bfloat162float(*(const bf16*)(bufC + swz(p, col * 2, 256)));
            sr = fmaf(x, w_rgb[0 * 128 + col], sr);
            sg = fmaf(x, w_rgb[1 * 128 + col], sg);
            sb = fmaf(x, w_rgb[2 * 128 + col], sb);
        }
        #pragma unroll
        for (int off = 4; off; off >>= 1) {
            sa += __shfl_xor(sa, off, 64);
            sr += __shfl_xor(sr, off, 64);
            sg += __shfl_xor(sg, off, 64);
            sb += __shfl_xor(sb, off, 64);
        }
        if (g == 0) {
            float4 o = make_float4(sa + b_alpha[0], sr + b_rgb[0], sg + b_rgb[1], sb + b_rgb[2]);
            *(float4*)(out + (size_t)(n0 + p) * 4) = o;
        }
    }
}

extern "C" void kernel_launch(void* const* d_in, const int* in_sizes, int n_in,
                              void* d_out, int out_size, void* d_ws, size_t ws_size,
                              hipStream_t stream) {
    (void)in_sizes; (void)n_in; (void)out_size; (void)ws_size;
    const float* sampled_pts  = (const float*)d_in[0];
    const float* smpl_verts   = (const float*)d_in[1];
    const float* view_dir     = (const float*)d_in[2];
    const float* input_latent = (const float*)d_in[3];
    const float* vts_uv       = (const float*)d_in[4];
    const float* w_geo0 = (const float*)d_in[5];
    const float* b_geo0 = (const float*)d_in[6];
    const float* w_geo1 = (const float*)d_in[7];
    const float* b_geo1 = (const float*)d_in[8];
    const float* w_alpha = (const float*)d_in[9];
    const float* b_alpha = (const float*)d_in[10];
    const float* w_view0 = (const float*)d_in[11];
    const float* b_view0 = (const float*)d_in[12];
    const float* w_view1 = (const float*)d_in[13];
    const float* b_view1 = (const float*)d_in[14];
    const float* w_rgb = (const float*)d_in[15];
    const float* b_rgb = (const float*)d_in[16];

    char* ws = (char*)d_ws;
    size_t off = 0;
    auto alloc = [&](size_t bytes) { void* p = ws + off; off += (bytes + 255) & ~(size_t)255; return p; };
    bf16*  latT = (bf16*)alloc((size_t)C_LAT * RESO * RESO * 2);   // 25.2 MB
    float* pd2  = (float*)alloc((size_t)N_PTS * NCHUNK * 4);       // 1 MB
    int*   pidx = (int*)alloc((size_t)N_PTS * NCHUNK * 4);         // 1 MB
    bf16*  W0b  = (bf16*)alloc((size_t)256 * 128 * 2);
    bf16*  W1b  = (bf16*)alloc((size_t)256 * 256 * 2);
    bf16*  W2b  = (bf16*)alloc((size_t)256 * 384 * 2);
    bf16*  W3b  = (bf16*)alloc((size_t)128 * 256 * 2);

    float* out = (float*)d_out;

    hipLaunchKernelGGL(fused_pre, dim3(NB_T + NB_N + NB_W), dim3(256), 0, stream,
                       input_latent, sampled_pts, smpl_verts,
                       w_geo0, w_geo1, w_view0, w_view1,
                       latT, pd2, pidx, W0b, W1b, W2b, W3b);
    hipLaunchKernelGGL(mega_lite, dim3(N_PTS / 64), dim3(512), 0, stream,
                       pd2, pidx, vts_uv, latT, view_dir,
                       W0b, b_geo0, W1b, b_geo1, W2b, b_view0, W3b, b_view1,
                       w_alpha, b_alpha, w_rgb, b_rgb, out);
}